// Round 2
// baseline (357.593 us; speedup 1.0000x reference)
//
#include <hip/hip_runtime.h>
#include <hip/hip_bf16.h>

#define T_DIM 2048
#define S_DIM 2048
#define B_DIM 4
#define H_DIM 8
#define HID   256
#define NTOK  (T_DIM*B_DIM)
#define LOG2E 1.44269504088896340736f

typedef __attribute__((ext_vector_type(8))) short bf16x8;
typedef __attribute__((ext_vector_type(4))) float f32x4;
typedef __attribute__((ext_vector_type(2))) unsigned int u32x2;

static __device__ __forceinline__ short f2bf(float f){
    unsigned u = __builtin_bit_cast(unsigned, f);
    u = (u + 0x7FFFu + ((u >> 16) & 1u)) >> 16;
    return (short)u;
}

static __device__ __forceinline__ unsigned cvt_pk_bf16(float lo, float hi){
    unsigned r;
    asm("v_cvt_pk_bf16_f32 %0, %1, %2" : "=v"(r) : "v"(lo), "v"(hi));
    return r;
}

// ---------------- weight prep: fp32 -> bf16, transposed to K-major ----------------
__global__ void prep_weights(const float* Wq1, const float* Wk1, const float* Wv1,
                             const float* Wq2, const float* Wk2, const float* Wv2,
                             const float* Wo,
                             short* W1t, short* W2t, short* Wot)
{
    int gid = blockIdx.x * blockDim.x + threadIdx.x;
    int stride = gridDim.x * blockDim.x;
    for (int idx = gid; idx < 3 * HID * 64; idx += stride){
        int p = idx / (HID * 64); int o = idx % (HID * 64);
        int j = o >> 6, i = o & 63;
        const float* W = (p == 0) ? Wq1 : (p == 1) ? Wk1 : Wv1;
        W1t[idx] = f2bf(W[i * HID + j]);
    }
    for (int idx = gid; idx < 3 * 512 * HID; idx += stride){
        int p = idx / (512 * HID); int o = idx % (512 * HID);
        int n = o >> 8, k = o & 255;
        const float* W = (p == 0) ? Wq2 : (p == 1) ? Wk2 : Wv2;
        W2t[idx] = f2bf(W[k * 512 + n]);
    }
    for (int idx = gid; idx < 64 * 512; idx += stride){
        int n = idx >> 9, k = idx & 511;
        Wot[idx] = f2bf(Wo[k * 64 + n]);
    }
}

// ---------------- per-token 2-layer MLP projections (q/k/v) ----------------
// grid (NTOK/64, 3), 256 threads.
// q,k -> [b][h][t][64] (q pre-scaled by 0.125*LOG2E); v -> transposed [b][h][64 d][t]
__global__ __launch_bounds__(256) void proj_kernel(
    const float* query, const float* key, const float* value,
    const short* W1t_all, const short* W2t_all,
    const float* bq1, const float* bk1, const float* bv1,
    const float* bq2, const float* bk2, const float* bv2,
    short* q_bh, short* k_bh, short* vt_bh)
{
    int p = blockIdx.y;
    const float* X  = (p == 0) ? query : (p == 1) ? key : value;
    const short* W1 = W1t_all + p * HID * 64;
    const short* W2 = W2t_all + p * 512 * HID;
    const float* b1 = (p == 0) ? bq1 : (p == 1) ? bk1 : bv1;
    const float* b2 = (p == 0) ? bq2 : (p == 1) ? bk2 : bv2;
    short* OUT = (p == 0) ? q_bh : (p == 1) ? k_bh : vt_bh;
    float oscale = (p == 0) ? 0.125f * LOG2E : 1.0f;

    __shared__ short Hs[64 * HID];

    int tid = threadIdx.x;
    int wave = tid >> 6, lane = tid & 63;
    int lg = lane >> 4, lr = lane & 15;
    int tok0 = blockIdx.x * 64;

    const float* xrow = X + (tok0 + wave * 16 + lr) * 64;
    bf16x8 a0, a1;
    #pragma unroll
    for (int j = 0; j < 8; j++){
        a0[j] = f2bf(xrow[lg * 8 + j]);
        a1[j] = f2bf(xrow[32 + lg * 8 + j]);
    }

    f32x4 accH[16];
    #pragma unroll
    for (int nb = 0; nb < 16; nb++) accH[nb] = 0.f;
    #pragma unroll
    for (int nb = 0; nb < 16; nb++){
        const short* w = W1 + (nb * 16 + lr) * 64;
        bf16x8 wb0 = *(const bf16x8*)(w + lg * 8);
        bf16x8 wb1 = *(const bf16x8*)(w + 32 + lg * 8);
        accH[nb] = __builtin_amdgcn_mfma_f32_16x16x32_bf16(a0, wb0, accH[nb], 0, 0, 0);
        accH[nb] = __builtin_amdgcn_mfma_f32_16x16x32_bf16(a1, wb1, accH[nb], 0, 0, 0);
    }
    #pragma unroll
    for (int nb = 0; nb < 16; nb++){
        int col = nb * 16 + lr;
        float bias = b1[col];
        #pragma unroll
        for (int r = 0; r < 4; r++){
            int row = wave * 16 + lg * 4 + r;
            float hv = accH[nb][r] + bias;
            hv = hv > 0.f ? hv : 0.f;
            Hs[row * HID + (col ^ ((row & 7) << 3))] = f2bf(hv);
        }
    }
    int hrow = wave * 16 + lr;
    bf16x8 ha[8];
    #pragma unroll
    for (int ks = 0; ks < 8; ks++){
        int col = ks * 32 + lg * 8;
        ha[ks] = *(const bf16x8*)(Hs + hrow * HID + (col ^ ((hrow & 7) << 3)));
    }

    if (p < 2){
        // swapped operands: D col = token, rows = n (r-consecutive) -> packed stores
        int token = tok0 + wave * 16 + lr;
        int t = token >> 2, bb = token & 3;
        #pragma unroll 1
        for (int nt = 0; nt < 8; nt++){
            f32x4 acc[4];
            #pragma unroll
            for (int nb = 0; nb < 4; nb++) acc[nb] = 0.f;
            #pragma unroll
            for (int ks = 0; ks < 8; ks++){
                #pragma unroll
                for (int nb = 0; nb < 4; nb++){
                    int n = nt * 64 + nb * 16 + lr;
                    bf16x8 wb = *(const bf16x8*)(W2 + n * HID + ks * 32 + lg * 8);
                    acc[nb] = __builtin_amdgcn_mfma_f32_16x16x32_bf16(wb, ha[ks], acc[nb], 0, 0, 0);
                }
            }
            #pragma unroll
            for (int nb = 0; nb < 4; nb++){
                f32x4 bias4 = *(const f32x4*)(b2 + nt * 64 + nb * 16 + lg * 4);
                float v0 = (acc[nb][0] + bias4[0]) * oscale;
                float v1 = (acc[nb][1] + bias4[1]) * oscale;
                float v2 = (acc[nb][2] + bias4[2]) * oscale;
                float v3 = (acc[nb][3] + bias4[3]) * oscale;
                u32x2 w;
                w[0] = cvt_pk_bf16(v0, v1);
                w[1] = cvt_pk_bf16(v2, v3);
                *(u32x2*)(OUT + ((bb * H_DIM + nt) * T_DIM + t) * 64 + nb * 16 + lg * 4) = w;
            }
        }
    } else {
        // V: original operand order; scalar stores into transposed [b][h][d][t]
        #pragma unroll 1
        for (int nt = 0; nt < 8; nt++){
            f32x4 acc[4];
            #pragma unroll
            for (int nb = 0; nb < 4; nb++) acc[nb] = 0.f;
            #pragma unroll
            for (int ks = 0; ks < 8; ks++){
                #pragma unroll
                for (int nb = 0; nb < 4; nb++){
                    int n = nt * 64 + nb * 16 + lr;
                    bf16x8 wb = *(const bf16x8*)(W2 + n * HID + ks * 32 + lg * 8);
                    acc[nb] = __builtin_amdgcn_mfma_f32_16x16x32_bf16(ha[ks], wb, acc[nb], 0, 0, 0);
                }
            }
            #pragma unroll
            for (int nb = 0; nb < 4; nb++){
                int d = nb * 16 + lr;
                float bias = b2[nt * 64 + d];
                #pragma unroll
                for (int r = 0; r < 4; r++){
                    int token = tok0 + wave * 16 + lg * 4 + r;
                    int t = token >> 2, bb = token & 3;
                    OUT[((bb * H_DIM + nt) * 64 + d) * S_DIM + t] = f2bf(acc[nb][r] + bias);
                }
            }
        }
    }
}

// ---------------- flash attention, fully swapped (lane-local softmax) ----------------
__global__ __launch_bounds__(256) void attn_kernel(
    const short* q_bh, const short* k_bh, const short* vt_bh,
    const float* mask, short* attn_buf)
{
    int bx = blockIdx.x;          // q tile (64 rows)
    int by = blockIdx.y;          // b*8 + h
    int b = by >> 3, h = by & 7;
    int tid = threadIdx.x, wave = tid >> 6, lane = tid & 63;
    int lg = lane >> 4, lr = lane & 15;

    const short* Qb  = q_bh  + by * (T_DIM * 64);
    const short* Kb  = k_bh  + by * (S_DIM * 64);
    const short* Vtb = vt_bh + by * (64 * S_DIM);

    __shared__ short Ks [64 * 64];     // [s][d], xor-swizzled
    __shared__ short Vts[64 * 64];     // [d][s], xor-swizzled
    __shared__ short Ps [4][16 * 64];  // per-wave P rows [q=lr][s], word-swizzled

    int qt = bx * 64 + wave * 16 + lr;              // this lane's q row
    const short* qrow = Qb + qt * 64;
    bf16x8 qa0 = *(const bf16x8*)(qrow + lg * 8);   // B-frag: col=q, k=d octet
    bf16x8 qa1 = *(const bf16x8*)(qrow + 32 + lg * 8);

    const float* mrow = mask + ((size_t)(b * T_DIM + qt)) * S_DIM;

    float m_l = -1e30f, lsum = 0.f;    // lane-local softmax state (log2 domain)
    f32x4 oacc[4];
    #pragma unroll
    for (int nb = 0; nb < 4; nb++) oacc[nb] = 0.f;

    int sK = tid >> 2, c0 = (tid & 3) * 16;     // staging: row, 16-col block
    int sw = (sK & 7) << 3;
    const short* ksrc = Kb  + sK * 64 + c0;     // + s0*64 per tile
    const short* vsrc = Vtb + sK * S_DIM + c0;  // + s0 per tile

    // prologue: stage tile 0
    bf16x8 kr0 = *(const bf16x8*)(ksrc);
    bf16x8 kr1 = *(const bf16x8*)(ksrc + 8);
    bf16x8 vr0 = *(const bf16x8*)(vsrc);
    bf16x8 vr1 = *(const bf16x8*)(vsrc + 8);
    *(bf16x8*)(Ks  + sK * 64 + ( c0      ^ sw)) = kr0;
    *(bf16x8*)(Ks  + sK * 64 + ((c0 + 8) ^ sw)) = kr1;
    *(bf16x8*)(Vts + sK * 64 + ( c0      ^ sw)) = vr0;
    *(bf16x8*)(Vts + sK * 64 + ((c0 + 8) ^ sw)) = vr1;
    __syncthreads();

    unsigned int* pw = (unsigned int*)&Ps[wave][lr * 64];
    int psw = (lr & 7) << 2;

    const int NT = S_DIM / 64;
    for (int st = 0; st < NT; st++){
        int s0 = st * 64;
        if (st + 1 < NT){   // T14: issue next-tile loads early
            kr0 = *(const bf16x8*)(ksrc + (s0 + 64) * 64);
            kr1 = *(const bf16x8*)(ksrc + (s0 + 64) * 64 + 8);
            vr0 = *(const bf16x8*)(vsrc + s0 + 64);
            vr1 = *(const bf16x8*)(vsrc + s0 + 64 + 8);
        }

        // QK^T swapped: D[s][q], col=q=lr, row = lg*4+r (s within 16-block)
        f32x4 sc[4];
        #pragma unroll
        for (int nb = 0; nb < 4; nb++){
            int n = nb * 16 + lr;
            int nsw = (lr & 7) << 3;
            bf16x8 kb0 = *(const bf16x8*)(Ks + n * 64 + (( lg * 8)      ^ nsw));
            bf16x8 kb1 = *(const bf16x8*)(Ks + n * 64 + ((32 + lg * 8)  ^ nsw));
            f32x4 z = {0.f, 0.f, 0.f, 0.f};
            z = __builtin_amdgcn_mfma_f32_16x16x32_bf16(kb0, qa0, z, 0, 0, 0);
            sc[nb] = __builtin_amdgcn_mfma_f32_16x16x32_bf16(kb1, qa1, z, 0, 0, 0);
        }

        // mask (float4) + lane-local softmax, log2 domain
        float pv[4][4];
        float rmax = -1e30f;
        #pragma unroll
        for (int nb = 0; nb < 4; nb++){
            f32x4 mk = *(const f32x4*)(mrow + s0 + nb * 16 + lg * 4);
            #pragma unroll
            for (int r = 0; r < 4; r++){
                float v = __builtin_fmaf(mk[r], LOG2E, sc[nb][r]);
                pv[nb][r] = v;
                rmax = fmaxf(rmax, v);
            }
        }
        rmax = fmaxf(rmax, __shfl_xor(rmax, 16, 64));
        rmax = fmaxf(rmax, __shfl_xor(rmax, 32, 64));
        float mnew = fmaxf(m_l, rmax);
        float scale = exp2f(m_l - mnew);
        float rsum = 0.f;
        #pragma unroll
        for (int nb = 0; nb < 4; nb++){
            #pragma unroll
            for (int r = 0; r < 4; r++){
                float e = exp2f(pv[nb][r] - mnew);
                pv[nb][r] = e;
                rsum += e;
            }
        }
        rsum += __shfl_xor(rsum, 16, 64);
        rsum += __shfl_xor(rsum, 32, 64);
        lsum = lsum * scale + rsum;
        m_l = mnew;
        #pragma unroll
        for (int nb = 0; nb < 4; nb++) oacc[nb] *= scale;

        // P -> per-wave LDS (packed b32, word-swizzled); row = q = lr
        #pragma unroll
        for (int nb = 0; nb < 4; nb++){
            #pragma unroll
            for (int hh = 0; hh < 2; hh++){
                unsigned w = cvt_pk_bf16(pv[nb][2 * hh], pv[nb][2 * hh + 1]);
                pw[(nb * 8 + lg * 2 + hh) ^ psw] = w;
            }
        }
        bf16x8 pa0 = *(const bf16x8*)(pw + (( lg * 4)      ^ psw));
        bf16x8 pa1 = *(const bf16x8*)(pw + ((16 + lg * 4)  ^ psw));

        // PV swapped: A = V^T rows (d), B = P cols (q); D col=q=lr, row=d local
        #pragma unroll
        for (int nb = 0; nb < 4; nb++){
            int d = nb * 16 + lr;
            int dsw = (lr & 7) << 3;
            bf16x8 vb0 = *(const bf16x8*)(Vts + d * 64 + (( lg * 8)      ^ dsw));
            bf16x8 vb1 = *(const bf16x8*)(Vts + d * 64 + ((32 + lg * 8)  ^ dsw));
            oacc[nb] = __builtin_amdgcn_mfma_f32_16x16x32_bf16(vb0, pa0, oacc[nb], 0, 0, 0);
            oacc[nb] = __builtin_amdgcn_mfma_f32_16x16x32_bf16(vb1, pa1, oacc[nb], 0, 0, 0);
        }
        __syncthreads();
        if (st + 1 < NT){   // write prefetched tile after barrier
            *(bf16x8*)(Ks  + sK * 64 + ( c0      ^ sw)) = kr0;
            *(bf16x8*)(Ks  + sK * 64 + ((c0 + 8) ^ sw)) = kr1;
            *(bf16x8*)(Vts + sK * 64 + ( c0      ^ sw)) = vr0;
            *(bf16x8*)(Vts + sK * 64 + ((c0 + 8) ^ sw)) = vr1;
            __syncthreads();
        }
    }

    // epilogue: O[q=lr][d = nb*16 + lg*4 + r] / lsum -> packed 8B stores
    float inv = 1.f / lsum;
    int token = qt * B_DIM + b;
    short* orow = attn_buf + token * 512 + h * 64;
    #pragma unroll
    for (int nb = 0; nb < 4; nb++){
        u32x2 w;
        w[0] = cvt_pk_bf16(oacc[nb][0] * inv, oacc[nb][1] * inv);
        w[1] = cvt_pk_bf16(oacc[nb][2] * inv, oacc[nb][3] * inv);
        *(u32x2*)(orow + nb * 16 + lg * 4) = w;
    }
}

// ---------------- output projection: [8192,512] @ Wo[512,64] + bo ----------------
__global__ __launch_bounds__(256) void oproj_kernel(const short* attn_buf, const short* Wot,
                                                    const float* bo, float* out)
{
    int tid = threadIdx.x, wave = tid >> 6, lane = tid & 63;
    int lg = lane >> 4, lr = lane & 15;
    int tok0 = blockIdx.x * 64;
    int token = tok0 + wave * 16 + lr;
    const short* arow = attn_buf + token * 512;
    f32x4 acc[4];
    #pragma unroll
    for (int nb = 0; nb < 4; nb++) acc[nb] = 0.f;
    #pragma unroll 4
    for (int ks = 0; ks < 16; ks++){
        bf16x8 a = *(const bf16x8*)(arow + ks * 32 + lg * 8);
        #pragma unroll
        for (int nb = 0; nb < 4; nb++){
            bf16x8 wb = *(const bf16x8*)(Wot + (nb * 16 + lr) * 512 + ks * 32 + lg * 8);
            acc[nb] = __builtin_amdgcn_mfma_f32_16x16x32_bf16(wb, a, acc[nb], 0, 0, 0);
        }
    }
    #pragma unroll
    for (int nb = 0; nb < 4; nb++){
        f32x4 bias4 = *(const f32x4*)(bo + nb * 16 + lg * 4);
        *(f32x4*)(out + token * 64 + nb * 16 + lg * 4) = acc[nb] + bias4;
    }
}

extern "C" void kernel_launch(void* const* d_in, const int* in_sizes, int n_in,
                              void* d_out, int out_size, void* d_ws, size_t ws_size,
                              hipStream_t stream)
{
    const float* query = (const float*)d_in[0];
    const float* key   = (const float*)d_in[1];
    const float* value = (const float*)d_in[2];
    const float* mask  = (const float*)d_in[3];
    const float* Wq1 = (const float*)d_in[4];  const float* bq1 = (const float*)d_in[5];
    const float* Wq2 = (const float*)d_in[6];  const float* bq2 = (const float*)d_in[7];
    const float* Wk1 = (const float*)d_in[8];  const float* bk1 = (const float*)d_in[9];
    const float* Wk2 = (const float*)d_in[10]; const float* bk2 = (const float*)d_in[11];
    const float* Wv1 = (const float*)d_in[12]; const float* bv1 = (const float*)d_in[13];
    const float* Wv2 = (const float*)d_in[14]; const float* bv2 = (const float*)d_in[15];
    const float* Wo  = (const float*)d_in[16]; const float* bo  = (const float*)d_in[17];

    short* ws      = (short*)d_ws;
    short* q_bh    = ws;                          // [4][8][2048][64] bf16 = 8 MB
    short* k_bh    = q_bh    + 4 * 1024 * 1024;   // 8 MB
    short* vt_bh   = k_bh    + 4 * 1024 * 1024;   // transposed [4][8][64][2048] = 8 MB
    short* attn_b  = vt_bh   + 4 * 1024 * 1024;   // [8192][512] bf16 = 8 MB
    short* W1t     = attn_b  + 4 * 1024 * 1024;
    short* W2t     = W1t     + 3 * HID * 64;
    short* Wot     = W2t     + 3 * 512 * HID;

    prep_weights<<<64, 256, 0, stream>>>(Wq1, Wk1, Wv1, Wq2, Wk2, Wv2, Wo, W1t, W2t, Wot);
    proj_kernel<<<dim3(NTOK / 64, 3), 256, 0, stream>>>(query, key, value, W1t, W2t,
                                                        bq1, bk1, bv1, bq2, bk2, bv2,
                                                        q_bh, k_bh, vt_bh);
    attn_kernel<<<dim3(T_DIM / 64, B_DIM * H_DIM), 256, 0, stream>>>(q_bh, k_bh, vt_bh, mask, attn_b);
    oproj_kernel<<<NTOK / 64, 256, 0, stream>>>(attn_b, Wot, bo, (float*)d_out);
}

// Round 3
// 297.679 us; speedup vs baseline: 1.2013x; 1.2013x over previous
//
#include <hip/hip_runtime.h>
#include <hip/hip_bf16.h>

#define T_DIM 2048
#define S_DIM 2048
#define B_DIM 4
#define H_DIM 8
#define HID   256
#define NTOK  (T_DIM*B_DIM)
#define LOG2E 1.44269504088896340736f

typedef __attribute__((ext_vector_type(8)))  short bf16x8;
typedef __attribute__((ext_vector_type(4)))  float f32x4;
typedef __attribute__((ext_vector_type(16))) float f32x16;
typedef __attribute__((ext_vector_type(2)))  unsigned int u32x2;
typedef __attribute__((ext_vector_type(4)))  unsigned int u32x4;

static __device__ __forceinline__ short f2bf(float f){
    unsigned u = __builtin_bit_cast(unsigned, f);
    u = (u + 0x7FFFu + ((u >> 16) & 1u)) >> 16;
    return (short)u;
}

static __device__ __forceinline__ unsigned cvt_pk_bf16(float lo, float hi){
    unsigned r;
    asm("v_cvt_pk_bf16_f32 %0, %1, %2" : "=v"(r) : "v"(lo), "v"(hi));
    return r;
}

// ---------------- weight prep: fp32 -> bf16, transposed to K-major ----------------
__global__ void prep_weights(const float* Wq1, const float* Wk1, const float* Wv1,
                             const float* Wq2, const float* Wk2, const float* Wv2,
                             const float* Wo,
                             short* W1t, short* W2t, short* Wot)
{
    int gid = blockIdx.x * blockDim.x + threadIdx.x;
    int stride = gridDim.x * blockDim.x;
    for (int idx = gid; idx < 3 * HID * 64; idx += stride){
        int p = idx / (HID * 64); int o = idx % (HID * 64);
        int j = o >> 6, i = o & 63;
        const float* W = (p == 0) ? Wq1 : (p == 1) ? Wk1 : Wv1;
        W1t[idx] = f2bf(W[i * HID + j]);
    }
    for (int idx = gid; idx < 3 * 512 * HID; idx += stride){
        int p = idx / (512 * HID); int o = idx % (512 * HID);
        int n = o >> 8, k = o & 255;
        const float* W = (p == 0) ? Wq2 : (p == 1) ? Wk2 : Wv2;
        W2t[idx] = f2bf(W[k * 512 + n]);
    }
    for (int idx = gid; idx < 64 * 512; idx += stride){
        int n = idx >> 9, k = idx & 511;
        Wot[idx] = f2bf(Wo[k * 64 + n]);
    }
}

// ---------------- per-token 2-layer MLP projections (q/k/v) ----------------
// grid (NTOK/64, 3, 2). Wave w owns tokens tok0 + tl*4 + w (tl=0..15) -> b == w.
// q,k -> [b][h][t][64] (q pre-scaled by 0.125*LOG2E); v -> [b][h][d][t] via LDS transpose.
__global__ __launch_bounds__(256) void proj_kernel(
    const float* query, const float* key, const float* value,
    const short* W1t_all, const short* W2t_all,
    const float* bq1, const float* bk1, const float* bv1,
    const float* bq2, const float* bk2, const float* bv2,
    short* q_bh, short* k_bh, short* vt_bh)
{
    int p = blockIdx.y;
    int nt0 = blockIdx.z * 4;                  // this block's 4 heads
    const float* X  = (p == 0) ? query : (p == 1) ? key : value;
    const short* W1 = W1t_all + p * HID * 64;
    const short* W2 = W2t_all + p * 512 * HID;
    const float* b1 = (p == 0) ? bq1 : (p == 1) ? bk1 : bv1;
    const float* b2 = (p == 0) ? bq2 : (p == 1) ? bk2 : bv2;
    float oscale = (p == 0) ? 0.125f * LOG2E : 1.0f;

    __shared__ short Hs[64 * HID];   // also reused as Vtmp[64][64] for p==2

    int tid = threadIdx.x;
    int wave = tid >> 6, lane = tid & 63;
    int lg = lane >> 4, lr = lane & 15;
    int tok0 = blockIdx.x * 64;

    // ---- A(=B)-frags of input X for this lane's token (tl = lr) ----
    const float* xrow = X + (tok0 + lr * 4 + wave) * 64;
    f32x4 x0 = *(const f32x4*)(xrow + lg * 8);
    f32x4 x1 = *(const f32x4*)(xrow + lg * 8 + 4);
    f32x4 x2 = *(const f32x4*)(xrow + 32 + lg * 8);
    f32x4 x3 = *(const f32x4*)(xrow + 32 + lg * 8 + 4);
    u32x4 awa, awb;
    awa[0] = cvt_pk_bf16(x0[0], x0[1]); awa[1] = cvt_pk_bf16(x0[2], x0[3]);
    awa[2] = cvt_pk_bf16(x1[0], x1[1]); awa[3] = cvt_pk_bf16(x1[2], x1[3]);
    awb[0] = cvt_pk_bf16(x2[0], x2[1]); awb[1] = cvt_pk_bf16(x2[2], x2[3]);
    awb[2] = cvt_pk_bf16(x3[0], x3[1]); awb[3] = cvt_pk_bf16(x3[2], x3[3]);
    bf16x8 a0 = __builtin_bit_cast(bf16x8, awa);
    bf16x8 a1 = __builtin_bit_cast(bf16x8, awb);

    // ---- layer 1 (swapped: D col = token) ----
    int hsrow = wave * 16 + lr;
    int hssw = (lr & 7) << 3;
    #pragma unroll
    for (int nb = 0; nb < 16; nb++){
        const short* w = W1 + (nb * 16 + lr) * 64;
        bf16x8 wb0 = *(const bf16x8*)(w + lg * 8);
        bf16x8 wb1 = *(const bf16x8*)(w + 32 + lg * 8);
        f32x4 acc = 0.f;
        acc = __builtin_amdgcn_mfma_f32_16x16x32_bf16(wb0, a0, acc, 0, 0, 0);
        acc = __builtin_amdgcn_mfma_f32_16x16x32_bf16(wb1, a1, acc, 0, 0, 0);
        f32x4 b4 = *(const f32x4*)(b1 + nb * 16 + lg * 4);
        float h0 = fmaxf(acc[0] + b4[0], 0.f);
        float h1 = fmaxf(acc[1] + b4[1], 0.f);
        float h2 = fmaxf(acc[2] + b4[2], 0.f);
        float h3 = fmaxf(acc[3] + b4[3], 0.f);
        u32x2 hw;
        hw[0] = cvt_pk_bf16(h0, h1);
        hw[1] = cvt_pk_bf16(h2, h3);
        *(u32x2*)(&Hs[hsrow * HID + ((nb * 16 + lg * 4) ^ hssw)]) = hw;
    }
    // layer-2 B-frags from own rows (wave-private, in-order DS -> no barrier)
    bf16x8 ha[8];
    #pragma unroll
    for (int ks = 0; ks < 8; ks++)
        ha[ks] = *(const bf16x8*)(&Hs[hsrow * HID + ((ks * 32 + lg * 8) ^ hssw)]);

    if (p < 2){
        short* OUT = (p == 0) ? q_bh : k_bh;
        int t = (tok0 >> 2) + lr;
        #pragma unroll 1
        for (int nt = nt0; nt < nt0 + 4; nt++){
            f32x4 acc[4];
            #pragma unroll
            for (int nb = 0; nb < 4; nb++) acc[nb] = 0.f;
            #pragma unroll
            for (int ks = 0; ks < 8; ks++){
                #pragma unroll
                for (int nb = 0; nb < 4; nb++){
                    int n = nt * 64 + nb * 16 + lr;
                    bf16x8 wb = *(const bf16x8*)(W2 + n * HID + ks * 32 + lg * 8);
                    acc[nb] = __builtin_amdgcn_mfma_f32_16x16x32_bf16(wb, ha[ks], acc[nb], 0, 0, 0);
                }
            }
            short* obase = OUT + ((wave * H_DIM + nt) * T_DIM + t) * 64;
            #pragma unroll
            for (int nb = 0; nb < 4; nb++){
                f32x4 b4 = *(const f32x4*)(b2 + nt * 64 + nb * 16 + lg * 4);
                u32x2 w;
                w[0] = cvt_pk_bf16((acc[nb][0] + b4[0]) * oscale, (acc[nb][1] + b4[1]) * oscale);
                w[1] = cvt_pk_bf16((acc[nb][2] + b4[2]) * oscale, (acc[nb][3] + b4[3]) * oscale);
                *(u32x2*)(obase + nb * 16 + lg * 4) = w;
            }
        }
    } else {
        // V: compute, then per-head LDS transpose -> coalesced [b][h][d][t] stores
        __syncthreads();   // all waves finished reading their Hs rows into ha
        int vrow = lr * 4 + wave;              // local token index
        int vsw = (vrow & 7) << 3;
        #pragma unroll 1
        for (int nt = nt0; nt < nt0 + 4; nt++){
            f32x4 acc[4];
            #pragma unroll
            for (int nb = 0; nb < 4; nb++) acc[nb] = 0.f;
            #pragma unroll
            for (int ks = 0; ks < 8; ks++){
                #pragma unroll
                for (int nb = 0; nb < 4; nb++){
                    int n = nt * 64 + nb * 16 + lr;
                    bf16x8 wb = *(const bf16x8*)(W2 + n * HID + ks * 32 + lg * 8);
                    acc[nb] = __builtin_amdgcn_mfma_f32_16x16x32_bf16(wb, ha[ks], acc[nb], 0, 0, 0);
                }
            }
            // write Vtmp[token_local][d] (d-run of 4 per lane, b64, swizzled)
            #pragma unroll
            for (int nb = 0; nb < 4; nb++){
                f32x4 b4 = *(const f32x4*)(b2 + nt * 64 + nb * 16 + lg * 4);
                u32x2 w;
                w[0] = cvt_pk_bf16(acc[nb][0] + b4[0], acc[nb][1] + b4[1]);
                w[1] = cvt_pk_bf16(acc[nb][2] + b4[2], acc[nb][3] + b4[3]);
                *(u32x2*)(&Hs[vrow * 64 + ((nb * 16 + lg * 4) ^ vsw)]) = w;
            }
            __syncthreads();
            // transposed read: thread = (d = lane, b = wave); 16 consecutive t -> 32B store
            {
                int d = lane;
                bf16x8 o0, o1;
                #pragma unroll
                for (int u = 0; u < 8; u++){
                    int row = 4 * u + wave;
                    o0[u] = Hs[row * 64 + (d ^ ((row & 7) << 3))];
                }
                #pragma unroll
                for (int u = 8; u < 16; u++){
                    int row = 4 * u + wave;
                    o1[u - 8] = Hs[row * 64 + (d ^ ((row & 7) << 3))];
                }
                short* dst = vt_bh + (((wave * H_DIM + nt) * 64 + d) * S_DIM) + (tok0 >> 2);
                *(bf16x8*)(dst)     = o0;
                *(bf16x8*)(dst + 8) = o1;
            }
            __syncthreads();
        }
    }
}

// ---------------- flash attention: 32x32 MFMA, P in-register ----------------
// grid (16, 32) -> swizzled so all 16 q-blocks of one (b,h) share an XCD.
__global__ __launch_bounds__(256) void attn_kernel(
    const short* q_bh, const short* k_bh, const short* vt_bh,
    const float* mask, short* attn_buf)
{
    // XCD-aware remap: physical id -> (bx, by) so one by's blocks stay on one XCD
    int pid = blockIdx.y * 16 + blockIdx.x;
    int xcd = pid & 7, c = pid >> 3;
    int by = xcd * 4 + (c >> 4);
    int bx = c & 15;

    int b = by >> 3, h = by & 7;
    int tid = threadIdx.x, wave = tid >> 6, lane = tid & 63;
    int l31 = lane & 31, hi = lane >> 5;

    const short* Qb  = q_bh  + by * (T_DIM * 64);
    const short* Kb  = k_bh  + by * (S_DIM * 64);
    const short* Vtb = vt_bh + by * (64 * S_DIM);

    __shared__ short Ks [2][64 * 64];
    __shared__ short Vts[2][64 * 64];

    int q = bx * 128 + wave * 32 + l31;
    const short* qrow = Qb + q * 64;
    bf16x8 qf[4];
    #pragma unroll
    for (int ks = 0; ks < 4; ks++)
        qf[ks] = *(const bf16x8*)(qrow + ks * 16 + hi * 8);

    const float* mrow = mask + (size_t)(b * T_DIM + q) * S_DIM;

    // staging: row = tid>>2, two 16B chunks at col (tid&3)*16 (+8)
    int srow = tid >> 2, scol = (tid & 3) * 16;
    int ssw = (srow & 7) << 3;
    const short* ksrc = Kb  + srow * 64 + scol;
    const short* vsrc = Vtb + srow * S_DIM + scol;

    float m_l = -1e30f, lsum = 0.f;
    f32x16 oacc[2];
    oacc[0] = 0.f; oacc[1] = 0.f;

    // prologue: tile 0
    bf16x8 kA = *(const bf16x8*)(ksrc);
    bf16x8 kB = *(const bf16x8*)(ksrc + 8);
    bf16x8 vA = *(const bf16x8*)(vsrc);
    bf16x8 vB = *(const bf16x8*)(vsrc + 8);
    *(bf16x8*)(&Ks [0][srow * 64 + ( scol      ^ ssw)]) = kA;
    *(bf16x8*)(&Ks [0][srow * 64 + ((scol + 8) ^ ssw)]) = kB;
    *(bf16x8*)(&Vts[0][srow * 64 + ( scol      ^ ssw)]) = vA;
    *(bf16x8*)(&Vts[0][srow * 64 + ((scol + 8) ^ ssw)]) = vB;
    f32x4 mk[8];
    #pragma unroll
    for (int sb = 0; sb < 2; sb++)
        #pragma unroll
        for (int mm = 0; mm < 4; mm++)
            mk[sb * 4 + mm] = *(const f32x4*)(mrow + sb * 32 + mm * 8 + hi * 4);
    __syncthreads();

    int cur = 0;
    #pragma unroll 1
    for (int st = 0; st < S_DIM / 64; st++){
        int s0 = st * 64;
        if (st < 31){   // issue next-tile K/V loads (consumed at end of this iter)
            kA = *(const bf16x8*)(ksrc + (s0 + 64) * 64);
            kB = *(const bf16x8*)(ksrc + (s0 + 64) * 64 + 8);
            vA = *(const bf16x8*)(vsrc + s0 + 64);
            vB = *(const bf16x8*)(vsrc + s0 + 64 + 8);
        }

        // QK^T swapped: D[s][q], col=q=l31, 16 regs per 32-s block
        f32x16 sc[2];
        sc[0] = 0.f; sc[1] = 0.f;
        __builtin_amdgcn_s_setprio(1);
        #pragma unroll
        for (int sb = 0; sb < 2; sb++){
            int row = sb * 32 + l31;
            int sw = (row & 7) << 3;
            #pragma unroll
            for (int ks = 0; ks < 4; ks++){
                bf16x8 kb = *(const bf16x8*)(&Ks[cur][row * 64 + ((ks * 16 + hi * 8) ^ sw)]);
                sc[sb] = __builtin_amdgcn_mfma_f32_32x32x16_bf16(kb, qf[ks], sc[sb], 0, 0, 0);
            }
        }
        __builtin_amdgcn_s_setprio(0);

        // mask (log2 domain) + lane-local softmax over 32 values
        #pragma unroll
        for (int i = 0; i < 16; i++){
            sc[0][i] = __builtin_fmaf(mk[(i >> 2)][i & 3], LOG2E, sc[0][i]);
            sc[1][i] = __builtin_fmaf(mk[4 + (i >> 2)][i & 3], LOG2E, sc[1][i]);
        }
        float pmax = sc[0][0];
        #pragma unroll
        for (int i = 1; i < 16; i++) pmax = fmaxf(pmax, sc[0][i]);
        #pragma unroll
        for (int i = 0; i < 16; i++) pmax = fmaxf(pmax, sc[1][i]);
        pmax = fmaxf(pmax, __shfl_xor(pmax, 32, 64));
        if (__any(pmax > m_l + 8.f)){      // defer-max: rescale only on real growth
            float mnew = fmaxf(m_l, pmax);
            float scale = __builtin_amdgcn_exp2f(m_l - mnew);
            lsum *= scale;
            oacc[0] *= scale;
            oacc[1] *= scale;
            m_l = mnew;
        }
        float rsum = 0.f;
        #pragma unroll
        for (int i = 0; i < 16; i++){
            sc[0][i] = __builtin_amdgcn_exp2f(sc[0][i] - m_l); rsum += sc[0][i];
        }
        #pragma unroll
        for (int i = 0; i < 16; i++){
            sc[1][i] = __builtin_amdgcn_exp2f(sc[1][i] - m_l); rsum += sc[1][i];
        }
        rsum += __shfl_xor(rsum, 32, 64);
        lsum += rsum;

        if (st < 31){   // prefetch next tile's mask (after last use of mk)
            #pragma unroll
            for (int sb = 0; sb < 2; sb++)
                #pragma unroll
                for (int mm = 0; mm < 4; mm++)
                    mk[sb * 4 + mm] = *(const f32x4*)(mrow + s0 + 64 + sb * 32 + mm * 8 + hi * 4);
        }

        // P -> bf16 B-frags fully in-register (cvt_pk + cross-half shuffle)
        bf16x8 pb[4];
        #pragma unroll
        for (int ks = 0; ks < 4; ks++){
            int sb = ks >> 1, rb = (ks & 1) * 8;
            unsigned own01 = cvt_pk_bf16(sc[sb][rb + 0], sc[sb][rb + 1]);
            unsigned own23 = cvt_pk_bf16(sc[sb][rb + 2], sc[sb][rb + 3]);
            unsigned own45 = cvt_pk_bf16(sc[sb][rb + 4], sc[sb][rb + 5]);
            unsigned own67 = cvt_pk_bf16(sc[sb][rb + 6], sc[sb][rb + 7]);
            unsigned sw01 = (unsigned)__shfl_xor((int)own01, 32, 64);
            unsigned sw23 = (unsigned)__shfl_xor((int)own23, 32, 64);
            unsigned sw45 = (unsigned)__shfl_xor((int)own45, 32, 64);
            unsigned sw67 = (unsigned)__shfl_xor((int)own67, 32, 64);
            u32x4 pw;
            pw[0] = hi ? sw45 : own01;
            pw[1] = hi ? sw67 : own23;
            pw[2] = hi ? own45 : sw01;
            pw[3] = hi ? own67 : sw23;
            pb[ks] = __builtin_bit_cast(bf16x8, pw);
        }

        // PV swapped: A = V^T rows (d), B = P; D col=q
        __builtin_amdgcn_s_setprio(1);
        #pragma unroll
        for (int db = 0; db < 2; db++){
            int row = db * 32 + l31;
            int sw = (row & 7) << 3;
            #pragma unroll
            for (int ks = 0; ks < 4; ks++){
                bf16x8 vb = *(const bf16x8*)(&Vts[cur][row * 64 + ((ks * 16 + hi * 8) ^ sw)]);
                oacc[db] = __builtin_amdgcn_mfma_f32_32x32x16_bf16(vb, pb[ks], oacc[db], 0, 0, 0);
            }
        }
        __builtin_amdgcn_s_setprio(0);

        if (st < 31){   // write prefetched tile to the other buffer
            *(bf16x8*)(&Ks [cur ^ 1][srow * 64 + ( scol      ^ ssw)]) = kA;
            *(bf16x8*)(&Ks [cur ^ 1][srow * 64 + ((scol + 8) ^ ssw)]) = kB;
            *(bf16x8*)(&Vts[cur ^ 1][srow * 64 + ( scol      ^ ssw)]) = vA;
            *(bf16x8*)(&Vts[cur ^ 1][srow * 64 + ((scol + 8) ^ ssw)]) = vB;
        }
        __syncthreads();
        cur ^= 1;
    }

    // epilogue: O[q][d], d = db*32 + 8*mm + 4*hi + c -> packed 8B stores
    float inv = 1.f / lsum;
    int token = q * B_DIM + b;
    short* orow = attn_buf + (size_t)token * 512 + h * 64;
    #pragma unroll
    for (int db = 0; db < 2; db++){
        #pragma unroll
        for (int mm = 0; mm < 4; mm++){
            u32x2 w;
            w[0] = cvt_pk_bf16(oacc[db][4 * mm + 0] * inv, oacc[db][4 * mm + 1] * inv);
            w[1] = cvt_pk_bf16(oacc[db][4 * mm + 2] * inv, oacc[db][4 * mm + 3] * inv);
            *(u32x2*)(orow + db * 32 + mm * 8 + hi * 4) = w;
        }
    }
}

// ---------------- output projection: [8192,512] @ Wo[512,64] + bo ----------------
__global__ __launch_bounds__(256) void oproj_kernel(const short* attn_buf, const short* Wot,
                                                    const float* bo, float* out)
{
    int tid = threadIdx.x, wave = tid >> 6, lane = tid & 63;
    int lg = lane >> 4, lr = lane & 15;
    int tok0 = blockIdx.x * 64;
    int token = tok0 + wave * 16 + lr;
    const short* arow = attn_buf + token * 512;
    f32x4 acc[4];
    #pragma unroll
    for (int nb = 0; nb < 4; nb++) acc[nb] = 0.f;
    #pragma unroll 4
    for (int ks = 0; ks < 16; ks++){
        bf16x8 a = *(const bf16x8*)(arow + ks * 32 + lg * 8);
        #pragma unroll
        for (int nb = 0; nb < 4; nb++){
            bf16x8 wb = *(const bf16x8*)(Wot + (nb * 16 + lr) * 512 + ks * 32 + lg * 8);
            acc[nb] = __builtin_amdgcn_mfma_f32_16x16x32_bf16(wb, a, acc[nb], 0, 0, 0);
        }
    }
    #pragma unroll
    for (int nb = 0; nb < 4; nb++){
        f32x4 bias4 = *(const f32x4*)(bo + nb * 16 + lg * 4);
        *(f32x4*)(out + token * 64 + nb * 16 + lg * 4) = acc[nb] + bias4;
    }
}

extern "C" void kernel_launch(void* const* d_in, const int* in_sizes, int n_in,
                              void* d_out, int out_size, void* d_ws, size_t ws_size,
                              hipStream_t stream)
{
    const float* query = (const float*)d_in[0];
    const float* key   = (const float*)d_in[1];
    const float* value = (const float*)d_in[2];
    const float* mask  = (const float*)d_in[3];
    const float* Wq1 = (const float*)d_in[4];  const float* bq1 = (const float*)d_in[5];
    const float* Wq2 = (const float*)d_in[6];  const float* bq2 = (const float*)d_in[7];
    const float* Wk1 = (const float*)d_in[8];  const float* bk1 = (const float*)d_in[9];
    const float* Wk2 = (const float*)d_in[10]; const float* bk2 = (const float*)d_in[11];
    const float* Wv1 = (const float*)d_in[12]; const float* bv1 = (const float*)d_in[13];
    const float* Wv2 = (const float*)d_in[14]; const float* bv2 = (const float*)d_in[15];
    const float* Wo  = (const float*)d_in[16]; const float* bo  = (const float*)d_in[17];

    short* ws      = (short*)d_ws;
    short* q_bh    = ws;                          // [4][8][2048][64] bf16 = 8 MB
    short* k_bh    = q_bh    + 4 * 1024 * 1024;   // 8 MB
    short* vt_bh   = k_bh    + 4 * 1024 * 1024;   // [4][8][64][2048] = 8 MB
    short* attn_b  = vt_bh   + 4 * 1024 * 1024;   // [8192][512] bf16 = 8 MB
    short* W1t     = attn_b  + 4 * 1024 * 1024;
    short* W2t     = W1t     + 3 * HID * 64;
    short* Wot     = W2t     + 3 * 512 * HID;

    prep_weights<<<64, 256, 0, stream>>>(Wq1, Wk1, Wv1, Wq2, Wk2, Wv2, Wo, W1t, W2t, Wot);
    proj_kernel<<<dim3(NTOK / 64, 3, 2), 256, 0, stream>>>(query, key, value, W1t, W2t,
                                                           bq1, bk1, bv1, bq2, bk2, bv2,
                                                           q_bh, k_bh, vt_bh);
    attn_kernel<<<dim3(16, 32), 256, 0, stream>>>(q_bh, k_bh, vt_bh, mask, attn_b);
    oproj_kernel<<<NTOK / 64, 256, 0, stream>>>(attn_b, Wot, bo, (float*)d_out);
}

// Round 4
// 287.645 us; speedup vs baseline: 1.2432x; 1.0349x over previous
//
#include <hip/hip_runtime.h>
#include <hip/hip_bf16.h>

#define T_DIM 2048
#define S_DIM 2048
#define B_DIM 4
#define H_DIM 8
#define HID   256
#define NTOK  (T_DIM*B_DIM)
#define LOG2E 1.44269504088896340736f

typedef __attribute__((ext_vector_type(8)))  short bf16x8;
typedef __attribute__((ext_vector_type(4)))  float f32x4;
typedef __attribute__((ext_vector_type(16))) float f32x16;
typedef __attribute__((ext_vector_type(2)))  unsigned int u32x2;
typedef __attribute__((ext_vector_type(4)))  unsigned int u32x4;

static __device__ __forceinline__ short f2bf(float f){
    unsigned u = __builtin_bit_cast(unsigned, f);
    u = (u + 0x7FFFu + ((u >> 16) & 1u)) >> 16;
    return (short)u;
}

static __device__ __forceinline__ unsigned cvt_pk_bf16(float lo, float hi){
    unsigned r;
    asm("v_cvt_pk_bf16_f32 %0, %1, %2" : "=v"(r) : "v"(lo), "v"(hi));
    return r;
}

// ---------------- weight prep: fp32 -> bf16, transposed to K-major ----------------
__global__ void prep_weights(const float* Wq1, const float* Wk1, const float* Wv1,
                             const float* Wq2, const float* Wk2, const float* Wv2,
                             const float* Wo,
                             short* W1t, short* W2t, short* Wot)
{
    int gid = blockIdx.x * blockDim.x + threadIdx.x;
    int stride = gridDim.x * blockDim.x;
    for (int idx = gid; idx < 3 * HID * 64; idx += stride){
        int p = idx / (HID * 64); int o = idx % (HID * 64);
        int j = o >> 6, i = o & 63;
        const float* W = (p == 0) ? Wq1 : (p == 1) ? Wk1 : Wv1;
        W1t[idx] = f2bf(W[i * HID + j]);
    }
    for (int idx = gid; idx < 3 * 512 * HID; idx += stride){
        int p = idx / (512 * HID); int o = idx % (512 * HID);
        int n = o >> 8, k = o & 255;
        const float* W = (p == 0) ? Wq2 : (p == 1) ? Wk2 : Wv2;
        W2t[idx] = f2bf(W[k * 512 + n]);
    }
    for (int idx = gid; idx < 64 * 512; idx += stride){
        int n = idx >> 9, k = idx & 511;
        Wot[idx] = f2bf(Wo[k * 64 + n]);
    }
}

// ---------------- per-token 2-layer MLP projections (q/k/v) ----------------
// grid (NTOK/64, 3, 2). Wave w owns tokens tok0 + tl*4 + w (tl=0..15) -> b == w.
// q,k -> [b][h][t][64] (q pre-scaled by 0.125*LOG2E); v -> [b][h][d][t] via LDS transpose.
__global__ __launch_bounds__(256) void proj_kernel(
    const float* query, const float* key, const float* value,
    const short* W1t_all, const short* W2t_all,
    const float* bq1, const float* bk1, const float* bv1,
    const float* bq2, const float* bk2, const float* bv2,
    short* q_bh, short* k_bh, short* vt_bh)
{
    int p = blockIdx.y;
    int nt0 = blockIdx.z * 4;                  // this block's 4 heads
    const float* X  = (p == 0) ? query : (p == 1) ? key : value;
    const short* W1 = W1t_all + p * HID * 64;
    const short* W2 = W2t_all + p * 512 * HID;
    const float* b1 = (p == 0) ? bq1 : (p == 1) ? bk1 : bv1;
    const float* b2 = (p == 0) ? bq2 : (p == 1) ? bk2 : bv2;
    float oscale = (p == 0) ? 0.125f * LOG2E : 1.0f;

    __shared__ short Hs[64 * HID];   // also reused as Vtmp[64][64] for p==2

    int tid = threadIdx.x;
    int wave = tid >> 6, lane = tid & 63;
    int lg = lane >> 4, lr = lane & 15;
    int tok0 = blockIdx.x * 64;

    // ---- A(=B)-frags of input X for this lane's token (tl = lr) ----
    const float* xrow = X + (tok0 + lr * 4 + wave) * 64;
    f32x4 x0 = *(const f32x4*)(xrow + lg * 8);
    f32x4 x1 = *(const f32x4*)(xrow + lg * 8 + 4);
    f32x4 x2 = *(const f32x4*)(xrow + 32 + lg * 8);
    f32x4 x3 = *(const f32x4*)(xrow + 32 + lg * 8 + 4);
    u32x4 awa, awb;
    awa[0] = cvt_pk_bf16(x0[0], x0[1]); awa[1] = cvt_pk_bf16(x0[2], x0[3]);
    awa[2] = cvt_pk_bf16(x1[0], x1[1]); awa[3] = cvt_pk_bf16(x1[2], x1[3]);
    awb[0] = cvt_pk_bf16(x2[0], x2[1]); awb[1] = cvt_pk_bf16(x2[2], x2[3]);
    awb[2] = cvt_pk_bf16(x3[0], x3[1]); awb[3] = cvt_pk_bf16(x3[2], x3[3]);
    bf16x8 a0 = __builtin_bit_cast(bf16x8, awa);
    bf16x8 a1 = __builtin_bit_cast(bf16x8, awb);

    // ---- layer 1 (swapped: D col = token) ----
    int hsrow = wave * 16 + lr;
    int hssw = (lr & 7) << 3;
    #pragma unroll
    for (int nb = 0; nb < 16; nb++){
        const short* w = W1 + (nb * 16 + lr) * 64;
        bf16x8 wb0 = *(const bf16x8*)(w + lg * 8);
        bf16x8 wb1 = *(const bf16x8*)(w + 32 + lg * 8);
        f32x4 acc = 0.f;
        acc = __builtin_amdgcn_mfma_f32_16x16x32_bf16(wb0, a0, acc, 0, 0, 0);
        acc = __builtin_amdgcn_mfma_f32_16x16x32_bf16(wb1, a1, acc, 0, 0, 0);
        f32x4 b4 = *(const f32x4*)(b1 + nb * 16 + lg * 4);
        float h0 = fmaxf(acc[0] + b4[0], 0.f);
        float h1 = fmaxf(acc[1] + b4[1], 0.f);
        float h2 = fmaxf(acc[2] + b4[2], 0.f);
        float h3 = fmaxf(acc[3] + b4[3], 0.f);
        u32x2 hw;
        hw[0] = cvt_pk_bf16(h0, h1);
        hw[1] = cvt_pk_bf16(h2, h3);
        *(u32x2*)(&Hs[hsrow * HID + ((nb * 16 + lg * 4) ^ hssw)]) = hw;
    }
    // layer-2 B-frags from own rows (wave-private, in-order DS -> no barrier)
    bf16x8 ha[8];
    #pragma unroll
    for (int ks = 0; ks < 8; ks++)
        ha[ks] = *(const bf16x8*)(&Hs[hsrow * HID + ((ks * 32 + lg * 8) ^ hssw)]);

    if (p < 2){
        short* OUT = (p == 0) ? q_bh : k_bh;
        int t = (tok0 >> 2) + lr;
        #pragma unroll 1
        for (int nt = nt0; nt < nt0 + 4; nt++){
            f32x4 acc[4];
            #pragma unroll
            for (int nb = 0; nb < 4; nb++) acc[nb] = 0.f;
            #pragma unroll
            for (int ks = 0; ks < 8; ks++){
                #pragma unroll
                for (int nb = 0; nb < 4; nb++){
                    int n = nt * 64 + nb * 16 + lr;
                    bf16x8 wb = *(const bf16x8*)(W2 + n * HID + ks * 32 + lg * 8);
                    acc[nb] = __builtin_amdgcn_mfma_f32_16x16x32_bf16(wb, ha[ks], acc[nb], 0, 0, 0);
                }
            }
            short* obase = OUT + ((wave * H_DIM + nt) * T_DIM + t) * 64;
            #pragma unroll
            for (int nb = 0; nb < 4; nb++){
                f32x4 b4 = *(const f32x4*)(b2 + nt * 64 + nb * 16 + lg * 4);
                u32x2 w;
                w[0] = cvt_pk_bf16((acc[nb][0] + b4[0]) * oscale, (acc[nb][1] + b4[1]) * oscale);
                w[1] = cvt_pk_bf16((acc[nb][2] + b4[2]) * oscale, (acc[nb][3] + b4[3]) * oscale);
                *(u32x2*)(obase + nb * 16 + lg * 4) = w;
            }
        }
    } else {
        // V: compute, then per-head LDS transpose -> coalesced [b][h][d][t] stores
        __syncthreads();   // all waves finished reading their Hs rows into ha
        int vrow = lr * 4 + wave;              // local token index
        int vsw = (vrow & 7) << 3;
        #pragma unroll 1
        for (int nt = nt0; nt < nt0 + 4; nt++){
            f32x4 acc[4];
            #pragma unroll
            for (int nb = 0; nb < 4; nb++) acc[nb] = 0.f;
            #pragma unroll
            for (int ks = 0; ks < 8; ks++){
                #pragma unroll
                for (int nb = 0; nb < 4; nb++){
                    int n = nt * 64 + nb * 16 + lr;
                    bf16x8 wb = *(const bf16x8*)(W2 + n * HID + ks * 32 + lg * 8);
                    acc[nb] = __builtin_amdgcn_mfma_f32_16x16x32_bf16(wb, ha[ks], acc[nb], 0, 0, 0);
                }
            }
            // write Vtmp[token_local][d] (d-run of 4 per lane, b64, swizzled)
            #pragma unroll
            for (int nb = 0; nb < 4; nb++){
                f32x4 b4 = *(const f32x4*)(b2 + nt * 64 + nb * 16 + lg * 4);
                u32x2 w;
                w[0] = cvt_pk_bf16(acc[nb][0] + b4[0], acc[nb][1] + b4[1]);
                w[1] = cvt_pk_bf16(acc[nb][2] + b4[2], acc[nb][3] + b4[3]);
                *(u32x2*)(&Hs[vrow * 64 + ((nb * 16 + lg * 4) ^ vsw)]) = w;
            }
            __syncthreads();
            // transposed read: thread = (d = lane, b = wave); 16 consecutive t -> 32B store
            {
                int d = lane;
                bf16x8 o0, o1;
                #pragma unroll
                for (int u = 0; u < 8; u++){
                    int row = 4 * u + wave;
                    o0[u] = Hs[row * 64 + (d ^ ((row & 7) << 3))];
                }
                #pragma unroll
                for (int u = 8; u < 16; u++){
                    int row = 4 * u + wave;
                    o1[u - 8] = Hs[row * 64 + (d ^ ((row & 7) << 3))];
                }
                short* dst = vt_bh + (((wave * H_DIM + nt) * 64 + d) * S_DIM) + (tok0 >> 2);
                *(bf16x8*)(dst)     = o0;
                *(bf16x8*)(dst + 8) = o1;
            }
            __syncthreads();
        }
    }
}

// ---------------- flash attention: 32x32 MFMA, in-block S-split (8 waves) ----------------
// grid (16, 32); waves 0-3 do KV s<1024, waves 4-7 do s>=1024; LDS combine at end.
__global__ __launch_bounds__(512) void attn_kernel(
    const short* q_bh, const short* k_bh, const short* vt_bh,
    const float* mask, short* attn_buf)
{
    // XCD-aware remap: physical id -> (bx, by) so one by's blocks stay on one XCD
    int pid = blockIdx.y * 16 + blockIdx.x;
    int xcd = pid & 7, c = pid >> 3;
    int by = xcd * 4 + (c >> 4);
    int bx = c & 15;

    int b = by >> 3, h = by & 7;
    int tid = threadIdx.x;
    int half = tid >> 8;                 // 0: s<1024, 1: s>=1024
    int tid4 = tid & 255;                // id within half
    int wave4 = tid4 >> 6;               // 0..3 = q sub-tile
    int lane = tid & 63;
    int l31 = lane & 31, hi = lane >> 5;

    const short* Qb  = q_bh  + by * (T_DIM * 64);
    const short* Kb  = k_bh  + by * (S_DIM * 64) + half * 1024 * 64;
    const short* Vtb = vt_bh + by * (64 * S_DIM) + half * 1024;

    __shared__ short Ks [2][2][64 * 64];    // [half][buf]
    __shared__ short Vts[2][2][64 * 64];
    __shared__ float MLs[4][32][2];

    int q = bx * 128 + wave4 * 32 + l31;
    const short* qrow = Qb + q * 64;
    bf16x8 qf[4];
    #pragma unroll
    for (int ks = 0; ks < 4; ks++)
        qf[ks] = *(const bf16x8*)(qrow + ks * 16 + hi * 8);

    const float* mrow = mask + (size_t)(b * T_DIM + q) * S_DIM + half * 1024;

    // staging: row = tid4>>2, two 16B chunks at col (tid4&3)*16 (+8)
    int srow = tid4 >> 2, scol = (tid4 & 3) * 16;
    int ssw = (srow & 7) << 3;
    const short* ksrc = Kb  + srow * 64 + scol;
    const short* vsrc = Vtb + srow * S_DIM + scol;

    float m_l = -1e30f, lsum = 0.f;
    f32x16 oacc[2];
    oacc[0] = 0.f; oacc[1] = 0.f;

    // prologue: tile 0 of this half
    bf16x8 kA = *(const bf16x8*)(ksrc);
    bf16x8 kB = *(const bf16x8*)(ksrc + 8);
    bf16x8 vA = *(const bf16x8*)(vsrc);
    bf16x8 vB = *(const bf16x8*)(vsrc + 8);
    *(bf16x8*)(&Ks [half][0][srow * 64 + ( scol      ^ ssw)]) = kA;
    *(bf16x8*)(&Ks [half][0][srow * 64 + ((scol + 8) ^ ssw)]) = kB;
    *(bf16x8*)(&Vts[half][0][srow * 64 + ( scol      ^ ssw)]) = vA;
    *(bf16x8*)(&Vts[half][0][srow * 64 + ((scol + 8) ^ ssw)]) = vB;
    f32x4 mk[8];
    #pragma unroll
    for (int sb = 0; sb < 2; sb++)
        #pragma unroll
        for (int mm = 0; mm < 4; mm++)
            mk[sb * 4 + mm] = *(const f32x4*)(mrow + sb * 32 + mm * 8 + hi * 4);
    __syncthreads();

    int cur = 0;
    #pragma unroll 1
    for (int it = 0; it < 16; it++){
        int s0 = it * 64;
        if (it < 15){   // issue next-tile K/V loads (consumed at end of this iter)
            kA = *(const bf16x8*)(ksrc + (s0 + 64) * 64);
            kB = *(const bf16x8*)(ksrc + (s0 + 64) * 64 + 8);
            vA = *(const bf16x8*)(vsrc + s0 + 64);
            vB = *(const bf16x8*)(vsrc + s0 + 64 + 8);
        }

        // QK^T swapped: D[s][q], col=q=l31, 16 regs per 32-s block
        f32x16 sc[2];
        sc[0] = 0.f; sc[1] = 0.f;
        __builtin_amdgcn_s_setprio(1);
        #pragma unroll
        for (int sb = 0; sb < 2; sb++){
            int row = sb * 32 + l31;
            int sw = (row & 7) << 3;
            #pragma unroll
            for (int ks = 0; ks < 4; ks++){
                bf16x8 kb = *(const bf16x8*)(&Ks[half][cur][row * 64 + ((ks * 16 + hi * 8) ^ sw)]);
                sc[sb] = __builtin_amdgcn_mfma_f32_32x32x16_bf16(kb, qf[ks], sc[sb], 0, 0, 0);
            }
        }
        __builtin_amdgcn_s_setprio(0);

        // mask (log2 domain) + lane-local softmax over 32 values
        #pragma unroll
        for (int i = 0; i < 16; i++){
            sc[0][i] = __builtin_fmaf(mk[(i >> 2)][i & 3], LOG2E, sc[0][i]);
            sc[1][i] = __builtin_fmaf(mk[4 + (i >> 2)][i & 3], LOG2E, sc[1][i]);
        }
        float pmax = sc[0][0];
        #pragma unroll
        for (int i = 1; i < 16; i++) pmax = fmaxf(pmax, sc[0][i]);
        #pragma unroll
        for (int i = 0; i < 16; i++) pmax = fmaxf(pmax, sc[1][i]);
        pmax = fmaxf(pmax, __shfl_xor(pmax, 32, 64));
        if (__any(pmax > m_l + 8.f)){      // defer-max
            float mnew = fmaxf(m_l, pmax);
            float scale = __builtin_amdgcn_exp2f(m_l - mnew);
            lsum *= scale;
            oacc[0] *= scale;
            oacc[1] *= scale;
            m_l = mnew;
        }
        float rsum = 0.f;
        #pragma unroll
        for (int i = 0; i < 16; i++){
            sc[0][i] = __builtin_amdgcn_exp2f(sc[0][i] - m_l); rsum += sc[0][i];
        }
        #pragma unroll
        for (int i = 0; i < 16; i++){
            sc[1][i] = __builtin_amdgcn_exp2f(sc[1][i] - m_l); rsum += sc[1][i];
        }
        rsum += __shfl_xor(rsum, 32, 64);
        lsum += rsum;

        if (it < 15){   // prefetch next tile's mask (after last use of mk)
            #pragma unroll
            for (int sb = 0; sb < 2; sb++)
                #pragma unroll
                for (int mm = 0; mm < 4; mm++)
                    mk[sb * 4 + mm] = *(const f32x4*)(mrow + s0 + 64 + sb * 32 + mm * 8 + hi * 4);
        }

        // P -> bf16 B-frags fully in-register (cvt_pk + cross-half shuffle)
        bf16x8 pb[4];
        #pragma unroll
        for (int ks = 0; ks < 4; ks++){
            int sb = ks >> 1, rb = (ks & 1) * 8;
            unsigned own01 = cvt_pk_bf16(sc[sb][rb + 0], sc[sb][rb + 1]);
            unsigned own23 = cvt_pk_bf16(sc[sb][rb + 2], sc[sb][rb + 3]);
            unsigned own45 = cvt_pk_bf16(sc[sb][rb + 4], sc[sb][rb + 5]);
            unsigned own67 = cvt_pk_bf16(sc[sb][rb + 6], sc[sb][rb + 7]);
            unsigned sw01 = (unsigned)__shfl_xor((int)own01, 32, 64);
            unsigned sw23 = (unsigned)__shfl_xor((int)own23, 32, 64);
            unsigned sw45 = (unsigned)__shfl_xor((int)own45, 32, 64);
            unsigned sw67 = (unsigned)__shfl_xor((int)own67, 32, 64);
            u32x4 pw;
            pw[0] = hi ? sw45 : own01;
            pw[1] = hi ? sw67 : own23;
            pw[2] = hi ? own45 : sw01;
            pw[3] = hi ? own67 : sw23;
            pb[ks] = __builtin_bit_cast(bf16x8, pw);
        }

        // PV swapped: A = V^T rows (d), B = P; D col=q
        __builtin_amdgcn_s_setprio(1);
        #pragma unroll
        for (int db = 0; db < 2; db++){
            int row = db * 32 + l31;
            int sw = (row & 7) << 3;
            #pragma unroll
            for (int ks = 0; ks < 4; ks++){
                bf16x8 vb = *(const bf16x8*)(&Vts[half][cur][row * 64 + ((ks * 16 + hi * 8) ^ sw)]);
                oacc[db] = __builtin_amdgcn_mfma_f32_32x32x16_bf16(vb, pb[ks], oacc[db], 0, 0, 0);
            }
        }
        __builtin_amdgcn_s_setprio(0);

        if (it < 15){   // write prefetched tile to the other buffer
            *(bf16x8*)(&Ks [half][cur ^ 1][srow * 64 + ( scol      ^ ssw)]) = kA;
            *(bf16x8*)(&Ks [half][cur ^ 1][srow * 64 + ((scol + 8) ^ ssw)]) = kB;
            *(bf16x8*)(&Vts[half][cur ^ 1][srow * 64 + ( scol      ^ ssw)]) = vA;
            *(bf16x8*)(&Vts[half][cur ^ 1][srow * 64 + ((scol + 8) ^ ssw)]) = vB;
        }
        __syncthreads();
        cur ^= 1;
    }

    // ---- combine the two halves (alias partial-O onto Ks/Vts, stride-68 pad) ----
    float* base = ((wave4 < 2) ? (float*)&Ks[0][0][0] : (float*)&Vts[0][0][0])
                  + (wave4 & 1) * 2176;
    if (half == 1){
        #pragma unroll
        for (int db = 0; db < 2; db++)
            #pragma unroll
            for (int mm = 0; mm < 4; mm++){
                f32x4 w = { oacc[db][4*mm+0], oacc[db][4*mm+1], oacc[db][4*mm+2], oacc[db][4*mm+3] };
                *(f32x4*)(base + l31 * 68 + db * 32 + mm * 8 + hi * 4) = w;
            }
        if (hi == 0){
            MLs[wave4][l31][0] = m_l;
            MLs[wave4][l31][1] = lsum;
        }
    }
    __syncthreads();
    if (half == 0){
        float m1 = MLs[wave4][l31][0];
        float l1 = MLs[wave4][l31][1];
        float mmax = fmaxf(m_l, m1);
        float s0 = __builtin_amdgcn_exp2f(m_l - mmax);
        float s1 = __builtin_amdgcn_exp2f(m1 - mmax);
        float inv = 1.f / (s0 * lsum + s1 * l1);
        int token = q * B_DIM + b;
        short* orow = attn_buf + (size_t)token * 512 + h * 64;
        #pragma unroll
        for (int db = 0; db < 2; db++){
            #pragma unroll
            for (int mm = 0; mm < 4; mm++){
                f32x4 part = *(const f32x4*)(base + l31 * 68 + db * 32 + mm * 8 + hi * 4);
                float o0 = (s0 * oacc[db][4*mm+0] + s1 * part[0]) * inv;
                float o1 = (s0 * oacc[db][4*mm+1] + s1 * part[1]) * inv;
                float o2 = (s0 * oacc[db][4*mm+2] + s1 * part[2]) * inv;
                float o3 = (s0 * oacc[db][4*mm+3] + s1 * part[3]) * inv;
                u32x2 w;
                w[0] = cvt_pk_bf16(o0, o1);
                w[1] = cvt_pk_bf16(o2, o3);
                *(u32x2*)(orow + db * 32 + mm * 8 + hi * 4) = w;
            }
        }
    }
}

// ---------------- output projection: K-split over 4 waves + LDS reduce ----------------
// grid 512, block 256. Block = 16 tokens; wave w handles K range [w*128, w*128+128).
__global__ __launch_bounds__(256) void oproj_kernel(const short* attn_buf, const short* Wot,
                                                    const float* bo, float* out)
{
    int tid = threadIdx.x, wave = tid >> 6, lane = tid & 63;
    int lg = lane >> 4, lr = lane & 15;
    int tok0 = blockIdx.x * 16;
    __shared__ float red[4][16][68];
    const short* arow = attn_buf + (size_t)(tok0 + lr) * 512;
    f32x4 acc[4];
    #pragma unroll
    for (int nb = 0; nb < 4; nb++) acc[nb] = 0.f;
    #pragma unroll
    for (int ksl = 0; ksl < 4; ksl++){
        int ks = wave * 4 + ksl;
        bf16x8 a = *(const bf16x8*)(arow + ks * 32 + lg * 8);
        #pragma unroll
        for (int nb = 0; nb < 4; nb++){
            bf16x8 wb = *(const bf16x8*)(Wot + (nb * 16 + lr) * 512 + ks * 32 + lg * 8);
            acc[nb] = __builtin_amdgcn_mfma_f32_16x16x32_bf16(wb, a, acc[nb], 0, 0, 0);
        }
    }
    #pragma unroll
    for (int nb = 0; nb < 4; nb++)
        *(f32x4*)(&red[wave][lr][nb * 16 + lg * 4]) = acc[nb];
    __syncthreads();
    // thread (wave=nb, lr, lg) sums the 4 partials for its f32x4 chunk
    f32x4 s = 0.f;
    #pragma unroll
    for (int w = 0; w < 4; w++)
        s += *(const f32x4*)(&red[w][lr][wave * 16 + lg * 4]);
    f32x4 b4 = *(const f32x4*)(bo + wave * 16 + lg * 4);
    *(f32x4*)(out + (size_t)(tok0 + lr) * 64 + wave * 16 + lg * 4) = s + b4;
}

extern "C" void kernel_launch(void* const* d_in, const int* in_sizes, int n_in,
                              void* d_out, int out_size, void* d_ws, size_t ws_size,
                              hipStream_t stream)
{
    const float* query = (const float*)d_in[0];
    const float* key   = (const float*)d_in[1];
    const float* value = (const float*)d_in[2];
    const float* mask  = (const float*)d_in[3];
    const float* Wq1 = (const float*)d_in[4];  const float* bq1 = (const float*)d_in[5];
    const float* Wq2 = (const float*)d_in[6];  const float* bq2 = (const float*)d_in[7];
    const float* Wk1 = (const float*)d_in[8];  const float* bk1 = (const float*)d_in[9];
    const float* Wk2 = (const float*)d_in[10]; const float* bk2 = (const float*)d_in[11];
    const float* Wv1 = (const float*)d_in[12]; const float* bv1 = (const float*)d_in[13];
    const float* Wv2 = (const float*)d_in[14]; const float* bv2 = (const float*)d_in[15];
    const float* Wo  = (const float*)d_in[16]; const float* bo  = (const float*)d_in[17];

    short* ws      = (short*)d_ws;
    short* q_bh    = ws;                          // [4][8][2048][64] bf16 = 8 MB
    short* k_bh    = q_bh    + 4 * 1024 * 1024;   // 8 MB
    short* vt_bh   = k_bh    + 4 * 1024 * 1024;   // [4][8][64][2048] = 8 MB
    short* attn_b  = vt_bh   + 4 * 1024 * 1024;   // [8192][512] bf16 = 8 MB
    short* W1t     = attn_b  + 4 * 1024 * 1024;
    short* W2t     = W1t     + 3 * HID * 64;
    short* Wot     = W2t     + 3 * 512 * HID;

    prep_weights<<<128, 256, 0, stream>>>(Wq1, Wk1, Wv1, Wq2, Wk2, Wv2, Wo, W1t, W2t, Wot);
    proj_kernel<<<dim3(NTOK / 64, 3, 2), 256, 0, stream>>>(query, key, value, W1t, W2t,
                                                           bq1, bk1, bv1, bq2, bk2, bv2,
                                                           q_bh, k_bh, vt_bh);
    attn_kernel<<<dim3(16, 32), 512, 0, stream>>>(q_bh, k_bh, vt_bh, mask, attn_b);
    oproj_kernel<<<NTOK / 16, 256, 0, stream>>>(attn_b, Wot, bo, (float*)d_out);
}